// Round 4
// baseline (462.877 us; speedup 1.0000x reference)
//
#include <hip/hip_runtime.h>

// LSTM cell, B=131072, IN=H=128, fp32 in/out.
// R6: persistent pipelined blocks. R5 post-mortem: occupancy 41->58% with dur
// UNCHANGED (127us) -> occupancy was never binding. Blocks are phase-serial
// (load burst -> barriers -> compute -> store -> exit), launched in lockstep,
// so HBM is fed in bursts; ~20us effective latency per ~2us of block work.
// Fix the SCHEDULE, not residency: grid=512 persistent blocks (2/CU), each
// does 8 tiles with a 2-deep pipeline: issue tile t+1 global loads BEFORE
// tile t's GEMM; As double-buffered (2x16KB); cbuf recycled in-place
// (read-c-store-then-write-cprev, same thread same addr). 2 barriers/tile.
// Tile math (BM=32, Bp layout, MFMA, epilogue transpose) unchanged from R5.

#define B_ROWS 131072
#define HDIM 128
#define BM 32
#define LDT 132     // padded LDS tile row stride (floats)
#define NBLK 512    // persistent blocks: 2 per CU
#define TPB 8       // tiles per block: 4096 tiles / 512 blocks

typedef __attribute__((ext_vector_type(4))) float f32x4;
typedef __attribute__((ext_vector_type(8))) short s16x8;

__device__ inline unsigned short f2bf(float f) {
    unsigned int u = __float_as_uint(f);
    u += 0x7fffu + ((u >> 16) & 1u);   // RNE (inputs finite)
    return (unsigned short)(u >> 16);
}

__device__ inline float frcp(float x) { return __builtin_amdgcn_rcpf(x); }
__device__ inline float fsigmoid(float x) { return frcp(1.0f + __expf(-x)); }
__device__ inline float ftanh(float x) { return 1.0f - 2.0f * frcp(__expf(2.0f * x) + 1.0f); }

// Bp layout (ushort idx): (((w*8 + kc)*4 + ni)*512) + t16*32 + q*8 + e
__global__ void prep_weights(const float* __restrict__ Wi, const float* __restrict__ Ui,
                             const float* __restrict__ Wf, const float* __restrict__ Uf,
                             const float* __restrict__ Wg, const float* __restrict__ Ug,
                             const float* __restrict__ Wo, const float* __restrict__ Uo,
                             unsigned short* __restrict__ Bp) {
    int idx = blockIdx.x * 256 + threadIdx.x;   // 0..131071
    int e   = idx & 7;
    int q   = (idx >> 3) & 3;
    int t16 = (idx >> 5) & 15;
    int ni  = (idx >> 9) & 3;
    int kc  = (idx >> 11) & 7;
    int w   = idx >> 14;
    int j = w * 16 + t16;
    int k = kc * 32 + q * 8 + e;
    const float* Wp = ni == 0 ? Wi : ni == 1 ? Wf : ni == 2 ? Wg : Wo;
    const float* Up = ni == 0 ? Ui : ni == 1 ? Uf : ni == 2 ? Ug : Uo;
    float v = (k < 128) ? Wp[k * HDIM + j] : Up[(k - 128) * HDIM + j];
    Bp[idx] = f2bf(v);
}

__global__ __launch_bounds__(512, 4) void lstm_main(
    const float* __restrict__ x, const float* __restrict__ h_prev,
    const float* __restrict__ c_prev,
    const unsigned short* __restrict__ Bp,
    const float* __restrict__ bi, const float* __restrict__ bf_,
    const float* __restrict__ bg, const float* __restrict__ bo,
    float* __restrict__ out)
{
    // LDS: As0 (16KB) | As1 (16KB) | cbuf 32x132 f32 | hbuf 32x132 f32 = 66560 B
    __shared__ float smem[8192 + 2 * BM * LDT];
    unsigned short* As0 = (unsigned short*)smem;
    unsigned short* As1 = (unsigned short*)(smem + 4096);
    float* cbuf = smem + 8192;
    float* hbuf = smem + 8192 + BM * LDT;

    const int tid = threadIdx.x;
    const int wave = tid >> 6;
    const int lane = tid & 63;
    const int t16 = lane & 15;
    const int q = lane >> 4;
    const int lane_off = t16 * 32 + q * 8;

    const int tile0 = blockIdx.x * TPB;

    // per-thread constants
    const int j = wave * 16 + t16;
    const float vbi = bi[j], vbf = bf_[j], vbg = bg[j], vbo = bo[j];
    const unsigned short* bbase = Bp + (size_t)(wave * 8) * 2048 + lane_off;
    float* hout = out;
    float* cout = out + (size_t)B_ROWS * HDIM;

    float4 sv[4], cv[2];

    // ---- prologue: load + stage tile0 into As0/cbuf
    {
        const int m0 = tile0 * BM;
        #pragma unroll
        for (int it = 0; it < 4; ++it) {
            int fi = it * 512 + tid; int r = fi >> 6; int c4 = fi & 63; int k0 = c4 * 4;
            const float* src = (k0 < 128) ? (x + (size_t)(m0 + r) * HDIM + k0)
                                          : (h_prev + (size_t)(m0 + r) * HDIM + (k0 - 128));
            sv[it] = *(const float4*)src;
        }
        #pragma unroll
        for (int it = 0; it < 2; ++it) {
            int f = it * 512 + tid; int r = f >> 5; int c4 = f & 31;
            cv[it] = *(const float4*)(c_prev + (size_t)(m0 + r) * HDIM + c4 * 4);
        }
        #pragma unroll
        for (int it = 0; it < 4; ++it) {
            int fi = it * 512 + tid; int r = fi >> 6; int c4 = fi & 63; int k0 = c4 * 4;
            ushort4 p;
            p.x = f2bf(sv[it].x); p.y = f2bf(sv[it].y); p.z = f2bf(sv[it].z); p.w = f2bf(sv[it].w);
            int mi = r >> 4, t16r = r & 15;
            int kc = k0 >> 5, qq = (k0 >> 3) & 3, e0 = k0 & 7;
            *(ushort4*)&As0[((mi * 8 + kc) * 16 + t16r) * 32 + qq * 8 + e0] = p;
        }
        #pragma unroll
        for (int it = 0; it < 2; ++it) {
            int f = it * 512 + tid; int r = f >> 5; int c4 = f & 31;
            *(float4*)&cbuf[r * LDT + c4 * 4] = cv[it];
        }
    }
    __syncthreads();

    #pragma unroll 2
    for (int t = 0; t < TPB; ++t) {
        const unsigned short* Ac = (t & 1) ? As1 : As0;   // current tile buffer
        unsigned short* An = (t & 1) ? As0 : As1;         // next tile buffer
        const bool have_next = (t + 1 < TPB);

        // ---- issue next tile's global loads FIRST (hide under GEMM+epilogue)
        if (have_next) {
            const int m0n = (tile0 + t + 1) * BM;
            #pragma unroll
            for (int it = 0; it < 4; ++it) {
                int fi = it * 512 + tid; int r = fi >> 6; int c4 = fi & 63; int k0 = c4 * 4;
                const float* src = (k0 < 128) ? (x + (size_t)(m0n + r) * HDIM + k0)
                                              : (h_prev + (size_t)(m0n + r) * HDIM + (k0 - 128));
                sv[it] = *(const float4*)src;
            }
            #pragma unroll
            for (int it = 0; it < 2; ++it) {
                int f = it * 512 + tid; int r = f >> 5; int c4 = f & 31;
                cv[it] = *(const float4*)(c_prev + (size_t)(m0n + r) * HDIM + c4 * 4);
            }
        }

        // ---- GEMM on tile t from As[cur]
        f32x4 acc[2][4];
        const f32x4 zero = {0.0f, 0.0f, 0.0f, 0.0f};
        #pragma unroll
        for (int mi = 0; mi < 2; ++mi)
            #pragma unroll
            for (int ni = 0; ni < 4; ++ni)
                acc[mi][ni] = zero;

        #pragma unroll
        for (int kc = 0; kc < 8; ++kc) {
            s16x8 a[2], b[4];
            #pragma unroll
            for (int ni = 0; ni < 4; ++ni)
                b[ni] = *(const s16x8*)(bbase + kc * 2048 + ni * 512);
            #pragma unroll
            for (int mi = 0; mi < 2; ++mi)
                a[mi] = *(const s16x8*)&Ac[(mi * 8 + kc) * 512 + lane_off];
            #pragma unroll
            for (int mi = 0; mi < 2; ++mi)
                #pragma unroll
                for (int ni = 0; ni < 4; ++ni)
                    acc[mi][ni] = __builtin_amdgcn_mfma_f32_16x16x32_bf16(a[mi], b[ni], acc[mi][ni], 0, 0, 0);
        }

        // ---- epilogue in MFMA layout: cp from cbuf, c->cbuf (own slot), h->hbuf
        #pragma unroll
        for (int mi = 0; mi < 2; ++mi) {
            #pragma unroll
            for (int r = 0; r < 4; ++r) {
                int rt = mi * 16 + q * 4 + r;
                float cp = cbuf[rt * LDT + j];
                float ig = fsigmoid(acc[mi][0][r] + vbi);
                float fg = fsigmoid(acc[mi][1][r] + vbf);
                float cc = ftanh(acc[mi][2][r] + vbg);
                float og = fsigmoid(acc[mi][3][r] + vbo);
                float c = fg * cp + ig * cc;
                float h = og * ftanh(c);
                hbuf[rt * LDT + j] = h;
                cbuf[rt * LDT + j] = c;            // own slot: read-before-write
            }
        }
        __syncthreads();   // b1: c/h tiles complete in LDS

        // ---- coalesced stores; recycle cbuf with next c_prev; stage As[next]
        {
            const int m0c = (tile0 + t) * BM;
            #pragma unroll
            for (int it = 0; it < 2; ++it) {
                int f = it * 512 + tid; int r = f >> 5; int c4 = f & 31;
                size_t goff = (size_t)(m0c + r) * HDIM + c4 * 4;
                float4 cc4 = *(const float4*)&cbuf[r * LDT + c4 * 4];
                *(float4*)(cout + goff) = cc4;
                if (have_next)
                    *(float4*)&cbuf[r * LDT + c4 * 4] = cv[it];   // same addr, after read
                *(float4*)(hout + goff) = *(const float4*)&hbuf[r * LDT + c4 * 4];
            }
            if (have_next) {
                #pragma unroll
                for (int it = 0; it < 4; ++it) {
                    int fi = it * 512 + tid; int r = fi >> 6; int c4 = fi & 63; int k0 = c4 * 4;
                    ushort4 p;
                    p.x = f2bf(sv[it].x); p.y = f2bf(sv[it].y); p.z = f2bf(sv[it].z); p.w = f2bf(sv[it].w);
                    int mi = r >> 4, t16r = r & 15;
                    int kc = k0 >> 5, qq = (k0 >> 3) & 3, e0 = k0 & 7;
                    *(ushort4*)&An[((mi * 8 + kc) * 16 + t16r) * 32 + qq * 8 + e0] = p;
                }
            }
        }
        __syncthreads();   // b2: cbuf holds c_prev[t+1], As[next] staged
    }
}

extern "C" void kernel_launch(void* const* d_in, const int* in_sizes, int n_in,
                              void* d_out, int out_size, void* d_ws, size_t ws_size,
                              hipStream_t stream) {
    const float* x      = (const float*)d_in[0];
    const float* h_prev = (const float*)d_in[1];
    const float* c_prev = (const float*)d_in[2];
    const float* Wi = (const float*)d_in[3];
    const float* Ui = (const float*)d_in[4];
    const float* bi = (const float*)d_in[5];
    const float* Wf = (const float*)d_in[6];
    const float* Uf = (const float*)d_in[7];
    const float* bf = (const float*)d_in[8];
    const float* Wg = (const float*)d_in[9];
    const float* Ug = (const float*)d_in[10];
    const float* bg = (const float*)d_in[11];
    const float* Wo = (const float*)d_in[12];
    const float* Uo = (const float*)d_in[13];
    const float* bo = (const float*)d_in[14];

    unsigned short* Bp = (unsigned short*)d_ws;   // 256 KB bf16 prepped weights

    prep_weights<<<512, 256, 0, stream>>>(Wi, Ui, Wf, Uf, Wg, Ug, Wo, Uo, Bp);
    lstm_main<<<NBLK, 512, 0, stream>>>(x, h_prev, c_prev, Bp, bi, bf, bg, bo, (float*)d_out);
}

// Round 5
// 451.192 us; speedup vs baseline: 1.0259x; 1.0259x over previous
//
#include <hip/hip_runtime.h>

// LSTM cell, B=131072, IN=H=128, fp32 in/out.
// R7: persistent pipeline, register-free prefetch. R6 post-mortem: holding
// sv[4]+cv[2] (24 regs) across GEMM spilled -> 180 MB scratch writes (matches
// WRITE +179 MB), FETCH +467 MB. Fix: prefetch next tile x/h as RAW fp32 via
// global_load_lds into a 32 KB LDS buffer (zero regs, async); convert to bf16
// As layout AFTER the single vmcnt-draining barrier (b2). Prefetch is issued
// AFTER the GEMM's Bp loads: vmcnt retires in order (m135), so any prefetch
// older than a Bp load would be force-drained at the kc=1 MFMA wait.
// Barriers b0/b1/b3 are raw s_barrier + lgkmcnt(0) only -> prefetch stays in
// flight across epilogue+stores. cv (c_prev, 8 regs) also post-GEMM, consumed
// post-b2 (cbuf refill moved after b2). LDS = As 16K (reused as h-tile fp32
// after GEMM) + Raw 32K + cbuf 32x132 = 66048 B -> 2 blocks/CU.

#define B_ROWS 131072
#define HDIM 128
#define BM 32
#define LDT 132     // padded cbuf row stride (floats); 2-way bank aliasing only
#define NBLK 512    // persistent blocks: 2 per CU
#define TPB 8       // tiles per block

typedef __attribute__((ext_vector_type(4))) float f32x4;
typedef __attribute__((ext_vector_type(8))) short s16x8;

__device__ inline unsigned short f2bf(float f) {
    unsigned int u = __float_as_uint(f);
    u += 0x7fffu + ((u >> 16) & 1u);   // RNE (inputs finite)
    return (unsigned short)(u >> 16);
}

__device__ inline float frcp(float x) { return __builtin_amdgcn_rcpf(x); }
__device__ inline float fsigmoid(float x) { return frcp(1.0f + __expf(-x)); }
__device__ inline float ftanh(float x) { return 1.0f - 2.0f * frcp(__expf(2.0f * x) + 1.0f); }

// lgkm-only barrier: does NOT drain vmcnt -> global_load_lds stays in flight.
__device__ __forceinline__ void bar_lgkm() {
    asm volatile("s_waitcnt lgkmcnt(0)" ::: "memory");
    __builtin_amdgcn_s_barrier();
    asm volatile("" ::: "memory");
}

// async 16B/lane global->LDS copy; LDS dest is wave-uniform base + lane*16.
__device__ __forceinline__ void load_lds16(const void* g, void* l) {
    __builtin_amdgcn_global_load_lds(
        (const __attribute__((address_space(1))) unsigned int*)g,
        (__attribute__((address_space(3))) unsigned int*)l, 16, 0, 0);
}

// Bp layout (ushort idx): (((w*8 + kc)*4 + ni)*512) + t16*32 + q*8 + e
__global__ void prep_weights(const float* __restrict__ Wi, const float* __restrict__ Ui,
                             const float* __restrict__ Wf, const float* __restrict__ Uf,
                             const float* __restrict__ Wg, const float* __restrict__ Ug,
                             const float* __restrict__ Wo, const float* __restrict__ Uo,
                             unsigned short* __restrict__ Bp) {
    int idx = blockIdx.x * 256 + threadIdx.x;   // 0..131071
    int e   = idx & 7;
    int q   = (idx >> 3) & 3;
    int t16 = (idx >> 5) & 15;
    int ni  = (idx >> 9) & 3;
    int kc  = (idx >> 11) & 7;
    int w   = idx >> 14;
    int j = w * 16 + t16;
    int k = kc * 32 + q * 8 + e;
    const float* Wp = ni == 0 ? Wi : ni == 1 ? Wf : ni == 2 ? Wg : Wo;
    const float* Up = ni == 0 ? Ui : ni == 1 ? Uf : ni == 2 ? Ug : Uo;
    float v = (k < 128) ? Wp[k * HDIM + j] : Up[(k - 128) * HDIM + j];
    Bp[idx] = f2bf(v);
}

// issue 32 KB raw prefetch: x tile (16 KB) then h tile (16 KB), linear in LDS.
__device__ __forceinline__ void issue_raw(const float* x, const float* h_prev,
                                          int m0, float* Raw, int wave, int lane) {
    const char* xb = (const char*)(x + (size_t)m0 * HDIM);
    const char* hb = (const char*)(h_prev + (size_t)m0 * HDIM);
    #pragma unroll
    for (int i = 0; i < 4; ++i) {
        int o = (wave * 4 + i) << 10;                       // 1 KB chunk per wave-instr
        const char* g = (o < 16384) ? (xb + o) : (hb + (o - 16384));
        load_lds16(g + lane * 16, (char*)Raw + o);
    }
}

// LDS->LDS convert: Raw fp32 [x rows 0..31 | h rows 0..31] -> bf16 As frag layout
__device__ __forceinline__ void convert_raw(const float* Raw, unsigned short* As, int tid) {
    #pragma unroll
    for (int it = 0; it < 4; ++it) {
        int fi = it * 512 + tid;               // 0..2047 float4s
        int r  = fi >> 6;                      // row 0..31
        int c4 = fi & 63;
        int k0 = c4 * 4;
        const float* src = (k0 < 128) ? (Raw + r * 128 + k0)
                                      : (Raw + 4096 + r * 128 + (k0 - 128));
        float4 v = *(const float4*)src;
        ushort4 p;
        p.x = f2bf(v.x); p.y = f2bf(v.y); p.z = f2bf(v.z); p.w = f2bf(v.w);
        int mi = r >> 4, t16r = r & 15;
        int kc = k0 >> 5, qq = (k0 >> 3) & 3, e0 = k0 & 7;
        *(ushort4*)&As[((mi * 8 + kc) * 16 + t16r) * 32 + qq * 8 + e0] = p;
    }
}

__global__ __launch_bounds__(512, 4) void lstm_main(
    const float* __restrict__ x, const float* __restrict__ h_prev,
    const float* __restrict__ c_prev,
    const unsigned short* __restrict__ Bp,
    const float* __restrict__ bi, const float* __restrict__ bf_,
    const float* __restrict__ bg, const float* __restrict__ bo,
    float* __restrict__ out)
{
    // LDS: As 16 KB (bf16 A-frags during GEMM; fp32 h-tile [32][128] after)
    //    | Raw 32 KB (fp32 x|h prefetch) | cbuf 32x132 fp32. Total 66048 B.
    __shared__ float smem[16512];
    unsigned short* As = (unsigned short*)smem;
    float* hb   = smem;                // h-tile view of As region, stride 128
    float* Raw  = smem + 4096;
    float* cbuf = smem + 12288;

    const int tid = threadIdx.x;
    const int wave = tid >> 6;
    const int lane = tid & 63;
    const int t16 = lane & 15;
    const int q = lane >> 4;
    const int lane_off = t16 * 32 + q * 8;
    const int tile0 = blockIdx.x * TPB;

    const int j = wave * 16 + t16;
    const float vbi = bi[j], vbf = bf_[j], vbg = bg[j], vbo = bo[j];
    const unsigned short* bbase = Bp + (size_t)(wave * 8) * 2048 + lane_off;
    float* hout = out;
    float* cout = out + (size_t)B_ROWS * HDIM;

    float4 cv[2];

    // ---- prologue: prefetch tile0 raw + c_prev, drain, convert, park cbuf
    issue_raw(x, h_prev, tile0 * BM, Raw, wave, lane);
    {
        const int m0 = tile0 * BM;
        #pragma unroll
        for (int it = 0; it < 2; ++it) {
            int f = it * 512 + tid, r = f >> 5, c4 = f & 31;
            cv[it] = *(const float4*)(c_prev + (size_t)(m0 + r) * HDIM + c4 * 4);
        }
    }
    __syncthreads();                       // drain vmcnt: Raw + cv complete
    convert_raw(Raw, As, tid);
    #pragma unroll
    for (int it = 0; it < 2; ++it) {
        int f = it * 512 + tid, r = f >> 5, c4 = f & 31;
        *(float4*)&cbuf[r * LDT + c4 * 4] = cv[it];
    }
    bar_lgkm();                            // As + cbuf visible to all waves

    #pragma unroll 1
    for (int t = 0; t < TPB; ++t) {
        const bool have_next = (t + 1 < TPB);

        // ---- GEMM tile t (Bp loads are the only VMEM here; L2-resident)
        f32x4 acc[2][4];
        const f32x4 zero = {0.0f, 0.0f, 0.0f, 0.0f};
        #pragma unroll
        for (int mi = 0; mi < 2; ++mi)
            #pragma unroll
            for (int ni = 0; ni < 4; ++ni)
                acc[mi][ni] = zero;

        #pragma unroll
        for (int kc = 0; kc < 8; ++kc) {
            s16x8 a[2], b[4];
            #pragma unroll
            for (int ni = 0; ni < 4; ++ni)
                b[ni] = *(const s16x8*)(bbase + kc * 2048 + ni * 512);
            #pragma unroll
            for (int mi = 0; mi < 2; ++mi)
                a[mi] = *(const s16x8*)&As[(mi * 8 + kc) * 512 + lane_off];
            #pragma unroll
            for (int mi = 0; mi < 2; ++mi)
                #pragma unroll
                for (int ni = 0; ni < 4; ++ni)
                    acc[mi][ni] = __builtin_amdgcn_mfma_f32_16x16x32_bf16(a[mi], b[ni], acc[mi][ni], 0, 0, 0);
        }

        // ---- issue prefetch for t+1 AFTER all GEMM VMEM (vmcnt ordering!)
        if (have_next) {
            const int m0n = (tile0 + t + 1) * BM;
            issue_raw(x, h_prev, m0n, Raw, wave, lane);
            #pragma unroll
            for (int it = 0; it < 2; ++it) {
                int f = it * 512 + tid, r = f >> 5, c4 = f & 31;
                cv[it] = *(const float4*)(c_prev + (size_t)(m0n + r) * HDIM + c4 * 4);
            }
        }

        bar_lgkm();   // b0: all waves done reading As; hb overwrite now safe

        // ---- epilogue in MFMA layout: cp from cbuf; h -> hb (=As), c -> cbuf
        #pragma unroll
        for (int mi = 0; mi < 2; ++mi) {
            #pragma unroll
            for (int r = 0; r < 4; ++r) {
                int rt = mi * 16 + q * 4 + r;
                float cp = cbuf[rt * LDT + j];
                float ig = fsigmoid(acc[mi][0][r] + vbi);
                float fg = fsigmoid(acc[mi][1][r] + vbf);
                float cc = ftanh(acc[mi][2][r] + vbg);
                float og = fsigmoid(acc[mi][3][r] + vbo);
                float c = fg * cp + ig * cc;
                float h = og * ftanh(c);
                hb[rt * 128 + j] = h;
                cbuf[rt * LDT + j] = c;
            }
        }

        bar_lgkm();   // b1: h/c tiles complete in LDS

        // ---- coalesced full-line float4 stores (prefetch still in flight)
        {
            const int m0c = (tile0 + t) * BM;
            #pragma unroll
            for (int it = 0; it < 2; ++it) {
                int f = it * 512 + tid, r = f >> 5, c4 = f & 31;
                size_t goff = (size_t)(m0c + r) * HDIM + c4 * 4;
                *(float4*)(cout + goff) = *(const float4*)&cbuf[r * LDT + c4 * 4];
                *(float4*)(hout + goff) = *(const float4*)&hb[r * 128 + c4 * 4];
            }
        }

        if (have_next) {
            __syncthreads();               // b2: THE drain — Raw/cv landed, LDS reads done
            convert_raw(Raw, As, tid);     // Raw -> bf16 As for tile t+1
            #pragma unroll
            for (int it = 0; it < 2; ++it) {
                int f = it * 512 + tid, r = f >> 5, c4 = f & 31;
                *(float4*)&cbuf[r * LDT + c4 * 4] = cv[it];   // c_prev[t+1]
            }
            bar_lgkm();                    // b3: As/cbuf ready for next iter
        }
    }
}

extern "C" void kernel_launch(void* const* d_in, const int* in_sizes, int n_in,
                              void* d_out, int out_size, void* d_ws, size_t ws_size,
                              hipStream_t stream) {
    const float* x      = (const float*)d_in[0];
    const float* h_prev = (const float*)d_in[1];
    const float* c_prev = (const float*)d_in[2];
    const float* Wi = (const float*)d_in[3];
    const float* Ui = (const float*)d_in[4];
    const float* bi = (const float*)d_in[5];
    const float* Wf = (const float*)d_in[6];
    const float* Uf = (const float*)d_in[7];
    const float* bf = (const float*)d_in[8];
    const float* Wg = (const float*)d_in[9];
    const float* Ug = (const float*)d_in[10];
    const float* bg = (const float*)d_in[11];
    const float* Wo = (const float*)d_in[12];
    const float* Uo = (const float*)d_in[13];
    const float* bo = (const float*)d_in[14];

    unsigned short* Bp = (unsigned short*)d_ws;   // 256 KB bf16 prepped weights

    prep_weights<<<512, 256, 0, stream>>>(Wi, Ui, Wf, Uf, Wg, Ug, Wo, Uo, Bp);
    lstm_main<<<NBLK, 512, 0, stream>>>(x, h_prev, c_prev, Bp, bi, bf, bg, bo, (float*)d_out);
}